// Round 5
// baseline (727.445 us; speedup 1.0000x reference)
//
#include <hip/hip_runtime.h>
#include <hip/hip_bf16.h>
#include <math.h>

typedef __hip_bfloat16 bf16;
typedef short bf16x8 __attribute__((ext_vector_type(8)));
typedef float f32x4 __attribute__((ext_vector_type(4)));

// ---------- bf16 helpers (bit-level, RNE pack) ----------
__device__ __forceinline__ float bfbits2f(unsigned int u) {
    union { unsigned int i; float f; } c; c.i = u << 16; return c.f;
}
__device__ __forceinline__ float b2f(const bf16 v) {
    return __bfloat162float(v);
}
__device__ __forceinline__ unsigned short f2bbits(float f) {
    unsigned int x = __float_as_uint(f);
    x += 0x7fffu + ((x >> 16) & 1u);   // round-to-nearest-even
    return (unsigned short)(x >> 16);
}
__device__ __forceinline__ void unpack8(const uint4 v, float* f) {
    f[0]=bfbits2f(v.x & 0xffffu); f[1]=bfbits2f(v.x >> 16);
    f[2]=bfbits2f(v.y & 0xffffu); f[3]=bfbits2f(v.y >> 16);
    f[4]=bfbits2f(v.z & 0xffffu); f[5]=bfbits2f(v.z >> 16);
    f[6]=bfbits2f(v.w & 0xffffu); f[7]=bfbits2f(v.w >> 16);
}

// ---------- tiny utility kernels ----------
__global__ void zero_k(float* p, int n) {
    int e = blockIdx.x * 256 + threadIdx.x;
    if (e < n) p[e] = 0.f;
}

// pack fp32 W[K][COUT] -> bf16 MFMA B-fragment layout:
// elem offset = ((kt2*NT + nt)*64 + lane)*8 + j  holds  W[kt2*32 + (lane>>4)*8 + j][nt*16 + (lane&15)]
__global__ void pack_k(const float* __restrict__ W, bf16* __restrict__ o,
                       const int K, const int COUT, const int NT, const int KP32) {
    const int e = blockIdx.x * 256 + threadIdx.x;
    const int total = KP32 * NT * 512;
    if (e >= total) return;
    const int j    = e & 7;
    const int lane = (e >> 3) & 63;
    const int rest = e >> 9;
    const int nt   = rest % NT;
    const int kt2  = rest / NT;
    const int k = kt2 * 32 + ((lane >> 4) << 3) + j;
    const int n = nt * 16 + (lane & 15);
    float v = (k < K && n < COUT) ? W[(size_t)k * COUT + n] : 0.f;
    union { unsigned short u; bf16 h; } c; c.u = f2bbits(v);
    o[e] = c.h;
}

// ---------- MFMA spiral conv, CIN>=64 (bf16 input) ----------
// 256 thr = 4 waves arranged WM x WN over a ROWS x COUT output tile.
// PF=3 register prefetch queue; one barrier per 64-wide k-chunk.
template<typename OT, int CIN, int COUT, int WN, bool ELU>
__global__ __launch_bounds__(256) void mconv_k(
    const bf16* __restrict__ x, const int* __restrict__ idx,
    const bf16* __restrict__ Wpk, const float* __restrict__ bias,
    OT* __restrict__ out, const int V, const int Vin)
{
    constexpr int K    = 9 * CIN;
    constexpr int NKC  = K / 64;          // 64-wide k-chunks
    constexpr int KS   = 2;               // MFMA k-steps per chunk
    constexpr int NT   = (COUT + 15) / 16;
    constexpr int NTW  = (WN == 2) ? NT / 2 : NT;
    constexpr int WM   = 4 / WN;
    constexpr int ROWS = WM * 16;
    constexpr int LPT  = ROWS / 32;       // uint4 stage-loads per thread (1 or 2)
    constexpr int PF   = 3;               // prefetch depth (chunks)

    __shared__ __align__(16) char alds[2][ROWS * 128];

    const int t = threadIdx.x, w = t >> 6, l = t & 63;
    const int r0 = blockIdx.x * ROWS;
    const int b  = r0 / V;
    const int v0 = r0 - b * V;
    const size_t bVin = (size_t)b * Vin;

    // staging geometry: thread covers 16B (LPT=1) or 32B (LPT=2) of one 128B row
    const int srow = (LPT == 1) ? (t >> 3) : (t >> 2);
    const int soff = (LPT == 1) ? ((t & 7) << 4) : ((t & 3) << 5);
    const int smsk = (srow & 7) << 4;

    // preload this staging-row's 9 neighbor indices (static accesses after unroll)
    const int* ip = idx + (v0 + srow) * 9;
    int nbr[9];
    #pragma unroll
    for (int s = 0; s < 9; ++s) nbr[s] = ip[s];

    f32x4 acc[NTW];
    #pragma unroll
    for (int nt = 0; nt < NTW; ++nt) acc[nt] = (f32x4){0.f, 0.f, 0.f, 0.f};

    uint4 qa[PF], qb[PF];

    // prologue: issue chunks 0..PF-1 (NKC >= 9 > PF always)
    #pragma unroll
    for (int p = 0; p < PF; ++p) {
        const int sc = (p * 64) / CIN, cic = (p * 64) % CIN;
        const bf16* gp = x + (bVin + nbr[sc]) * CIN + cic + (soff >> 1);
        qa[p] = *(const uint4*)gp;
        if constexpr (LPT == 2) qb[p] = *(const uint4*)(gp + 8);
    }
    // write chunk 0 into LDS buf 0
    {
        char* wb = alds[0] + srow * 128;
        *(uint4*)(wb + (soff ^ smsk)) = qa[0];
        if constexpr (LPT == 2) *(uint4*)(wb + ((soff + 16) ^ smsk)) = qb[0];
    }

    const int wm = (WN == 2) ? (w >> 1) : w;
    const int wn = (WN == 2) ? (w & 1) : 0;
    const int rl = (wm << 4) + (l & 15);
    const int rm = (rl & 7) << 4;
    const bf16x8* wpb = (const bf16x8*)Wpk;

    #pragma unroll
    for (int kt = 0; kt < NKC; ++kt) {
        // issue chunk kt+PF into the slot freed last iteration
        if (kt + PF < NKC) {
            const int c = kt + PF;
            const int sc = (c * 64) / CIN, cic = (c * 64) % CIN;
            const bf16* gp = x + (bVin + nbr[sc]) * CIN + cic + (soff >> 1);
            qa[c % PF] = *(const uint4*)gp;
            if constexpr (LPT == 2) qb[c % PF] = *(const uint4*)(gp + 8);
        }
        __syncthreads();   // all waves done reading buf (kt+1)&1 ; chunk kt writes visible
        // write chunk kt+1 (loaded PF-1 iters ago -> counted vmcnt wait)
        if (kt + 1 < NKC) {
            const int p = (kt + 1) % PF;
            char* wb = alds[(kt + 1) & 1] + srow * 128;
            *(uint4*)(wb + (soff ^ smsk)) = qa[p];
            if constexpr (LPT == 2) *(uint4*)(wb + ((soff + 16) ^ smsk)) = qb[p];
        }
        // compute chunk kt
        const char* ab = alds[kt & 1] + rl * 128;
        #pragma unroll
        for (int ks = 0; ks < KS; ++ks) {
            union { uint4 u; bf16x8 v; } af;
            af.u = *(const uint4*)(ab + ((ks * 64 + ((l >> 4) << 4)) ^ rm));
            const size_t wbase = ((size_t)(kt * KS + ks) * NT + wn * NTW) * 64 + l;
            #pragma unroll
            for (int nt = 0; nt < NTW; ++nt) {
                acc[nt] = __builtin_amdgcn_mfma_f32_16x16x32_bf16(
                    af.v, wpb[wbase + (size_t)nt * 64], acc[nt], 0, 0, 0);
            }
        }
    }

    // epilogue: bias + ELU + store (D: col=lane&15, row=(lane>>4)*4+rr)
    const int colg = l & 15;
    const int rg   = (l >> 4) << 2;
    #pragma unroll
    for (int nt = 0; nt < NTW; ++nt) {
        const int n = (wn * NTW + nt) * 16 + colg;
        if constexpr (COUT < 16) { if (n >= COUT) continue; }
        const float bv = bias[n];
        #pragma unroll
        for (int rr = 0; rr < 4; ++rr) {
            float a = acc[nt][rr] + bv;
            if constexpr (ELU) a = a > 0.f ? a : (__expf(a) - 1.f);
            const size_t o = (size_t)(r0 + (wm << 4) + rg + rr) * COUT + n;
            if constexpr (__is_same(OT, float)) {
                out[o] = a;
            } else {
                union { unsigned short u; bf16 h; } c; c.u = f2bbits(a);
                out[o] = c.h;
            }
        }
    }
}

// ---------- enc0: CIN=3 (fp32 input), K=27 padded to 32, single chunk ----------
__global__ __launch_bounds__(256) void mconv0_k(
    const float* __restrict__ x, const int* __restrict__ idx,
    const bf16* __restrict__ Wpk, const float* __restrict__ bias,
    bf16* __restrict__ out, const int V, const int Vin)
{
    __shared__ __align__(16) char alds[64 * 64];
    const int t = threadIdx.x, w = t >> 6, l = t & 63;
    const int r0 = blockIdx.x * 64;
    const int b  = r0 / V;
    const int v0 = r0 - b * V;

    *(uint4*)(alds + t * 16) = (uint4){0, 0, 0, 0};   // zero incl. k=27..31 pad
    __syncthreads();
    for (int e = t; e < 576; e += 256) {              // 64 rows x 9 spiral slots
        const int v = e / 9, s = e - v * 9;
        const int src = idx[(v0 + v) * 9 + s];
        const float* gp = x + ((size_t)b * Vin + src) * 3;
        const int m2 = (v & 3) << 4;
        char* base = alds + v * 64;
        #pragma unroll
        for (int j = 0; j < 3; ++j)
            *(unsigned short*)(base + (((s * 3 + j) * 2) ^ m2)) = f2bbits(gp[j]);
    }
    __syncthreads();

    const int rl = (w << 4) + (l & 15);
    const int rm = (rl & 3) << 4;
    union { uint4 u; bf16x8 v; } af;
    af.u = *(const uint4*)(alds + rl * 64 + ((((l >> 4) << 4)) ^ rm));
    const bf16x8* wpb = (const bf16x8*)Wpk;
    f32x4 acc[4];
    #pragma unroll
    for (int nt = 0; nt < 4; ++nt) {
        acc[nt] = (f32x4){0.f, 0.f, 0.f, 0.f};
        acc[nt] = __builtin_amdgcn_mfma_f32_16x16x32_bf16(af.v, wpb[(size_t)nt * 64 + l], acc[nt], 0, 0, 0);
    }
    const int colg = l & 15, rg = (l >> 4) << 2;
    #pragma unroll
    for (int nt = 0; nt < 4; ++nt) {
        const int n = nt * 16 + colg;
        const float bv = bias[n];
        #pragma unroll
        for (int rr = 0; rr < 4; ++rr) {
            float a = acc[nt][rr] + bv;
            a = a > 0.f ? a : (__expf(a) - 1.f);
            union { unsigned short u; bf16 h; } c; c.u = f2bbits(a);
            out[(size_t)(r0 + (w << 4) + rg + rr) * 64 + n] = c.h;
        }
    }
}

// ---------- pool: out[b,vo,c] = sum_k w[vo,k] * in[b, idx[vo,k], c] ----------
__global__ __launch_bounds__(256) void pool_k(
    const bf16* __restrict__ in, const int* __restrict__ idx,
    const float* __restrict__ w, bf16* __restrict__ out,
    const int Vout, const int Vin, const int C)
{
    const int nC8 = C >> 3;
    const long long total = (long long)16 * Vout * nC8;
    const long long gid = (long long)blockIdx.x * 256 + threadIdx.x;
    if (gid >= total) return;
    const int c8 = (int)(gid % nC8);
    const long long bv = gid / nC8;
    const int vo = (int)(bv % Vout);
    const int b  = (int)(bv / Vout);

    float r[8];
    #pragma unroll
    for (int u = 0; u < 8; ++u) r[u] = 0.f;
    #pragma unroll
    for (int jj = 0; jj < 3; ++jj) {
        const int src = idx[vo * 3 + jj];
        const float ww = w[vo * 3 + jj];
        const uint4 xv = *(const uint4*)(in + ((size_t)b * Vin + src) * C + c8 * 8);
        float f[8]; unpack8(xv, f);
        #pragma unroll
        for (int u = 0; u < 8; ++u) r[u] += ww * f[u];
    }
    uint4 st;
    st.x = f2bbits(r[0]) | ((unsigned)f2bbits(r[1]) << 16);
    st.y = f2bbits(r[2]) | ((unsigned)f2bbits(r[3]) << 16);
    st.z = f2bbits(r[4]) | ((unsigned)f2bbits(r[5]) << 16);
    st.w = f2bbits(r[6]) | ((unsigned)f2bbits(r[7]) << 16);
    *(uint4*)(out + ((size_t)b * Vout + vo) * C + c8 * 8) = st;
}

// ---------- z = F[16,81920] @ Wz[81920,256] (partial sums via atomics) ----------
__global__ __launch_bounds__(256) void zacc_k(
    const bf16* __restrict__ F, const float* __restrict__ Wz, float* __restrict__ zf)
{
    const int j  = threadIdx.x;          // output col
    const int i0 = blockIdx.x * 256;     // K-chunk
    float acc[16];
    #pragma unroll
    for (int b = 0; b < 16; ++b) acc[b] = 0.f;
    for (int i = i0; i < i0 + 256; i += 8) {
        float w[8];
        #pragma unroll
        for (int u = 0; u < 8; ++u) w[u] = Wz[(size_t)(i + u) * 256 + j];
        #pragma unroll
        for (int b = 0; b < 16; ++b) {
            const uint4 fv = *(const uint4*)(F + (size_t)b * 81920 + i);
            float f[8]; unpack8(fv, f);
            #pragma unroll
            for (int u = 0; u < 8; ++u) acc[b] += f[u] * w[u];
        }
    }
    #pragma unroll
    for (int b = 0; b < 16; ++b) atomicAdd(&zf[b * 256 + j], acc[b]);
}

// add bias, keep fp32 copy for decoder, emit fp32 z output
__global__ void zfin_k(float* __restrict__ zf, const float* __restrict__ bz,
                       float* __restrict__ outz)
{
    int e = blockIdx.x * 256 + threadIdx.x;  // 4096
    int j = e & 255;
    float v = zf[e] + bz[j];
    zf[e] = v;
    outz[e] = v;
}

// ---------- d[b,j] = sum_k z[b,k] * Wp[k,j] + bp[j] ----------
__global__ __launch_bounds__(256) void dproj_k(
    const float* __restrict__ zf, const float* __restrict__ Wp,
    const float* __restrict__ bp, bf16* __restrict__ d)
{
    __shared__ float zl[256][16];   // [k][b]
    const int t = threadIdx.x;
    #pragma unroll
    for (int b = 0; b < 16; ++b) zl[t][b] = zf[b * 256 + t];
    __syncthreads();
    const size_t j = (size_t)blockIdx.x * 256 + t;
    const float bpv = bp[j];
    float acc[16];
    #pragma unroll
    for (int b = 0; b < 16; ++b) acc[b] = bpv;
    for (int k = 0; k < 256; ++k) {
        const float w = Wp[(size_t)k * 81920 + j];
        #pragma unroll
        for (int b = 0; b < 16; ++b) acc[b] += zl[k][b] * w;
    }
    #pragma unroll
    for (int b = 0; b < 16; ++b) {
        union { unsigned short u; bf16 h; } c; c.u = f2bbits(acc[b]);
        d[(size_t)b * 81920 + j] = c.h;
    }
}

extern "C" void kernel_launch(void* const* d_in, const int* in_sizes, int n_in,
                              void* d_out, int out_size, void* d_ws, size_t ws_size,
                              hipStream_t stream) {
    (void)in_sizes; (void)n_in; (void)out_size; (void)ws_size;
    const float* x     = (const float*)d_in[0];
    const float* encW0 = (const float*)d_in[1];
    const float* encb0 = (const float*)d_in[2];
    const float* encW1 = (const float*)d_in[3];
    const float* encb1 = (const float*)d_in[4];
    const float* encW2 = (const float*)d_in[5];
    const float* encb2 = (const float*)d_in[6];
    const float* Wz    = (const float*)d_in[7];
    const float* bz    = (const float*)d_in[8];
    const float* Wp    = (const float*)d_in[9];
    const float* bp    = (const float*)d_in[10];
    const float* decW0 = (const float*)d_in[11];
    const float* decb0 = (const float*)d_in[12];
    const float* decW1 = (const float*)d_in[13];
    const float* decb1 = (const float*)d_in[14];
    const float* decW2 = (const float*)d_in[15];
    const float* decb2 = (const float*)d_in[16];
    const float* dpw0  = (const float*)d_in[17];
    const float* dpw1  = (const float*)d_in[18];
    const float* dpw2  = (const float*)d_in[19];
    const float* upw0  = (const float*)d_in[20];
    const float* upw1  = (const float*)d_in[21];
    const float* upw2  = (const float*)d_in[22];
    const int* idx0    = (const int*)d_in[23];
    const int* idx1    = (const int*)d_in[24];
    const int* idx2    = (const int*)d_in[25];
    const int* dpi0    = (const int*)d_in[26];
    const int* dpi1    = (const int*)d_in[27];
    const int* dpi2    = (const int*)d_in[28];
    const int* upi0    = (const int*)d_in[29];
    const int* upi1    = (const int*)d_in[30];
    const int* upi2    = (const int*)d_in[31];

    float* outy = (float*)d_out;        // [16,20480,3]
    float* outz = outy + 983040;        // [16,256]

    // ws layout:
    //  [0,16K)   zf fp32
    //  P = ws+32K : 20,971,520 bf16  (max use 21.0M only at enc0-out; <=10.5M after)
    //  Q = P+21M  : 20,971,520 bf16  (max 21.0M only at upool2-out)
    //  Wbig = Q+10,485,760 elems: packed enc0..dec1 weights (clobbered only by upool2,
    //         after dec1 consumed them).
    //  dec2pk = P+10,485,760 elems: packed just-in-time after dec1 (P<=5.24M then).
    char* ws  = (char*)d_ws;
    float* zf = (float*)ws;
    bf16* P   = (bf16*)(ws + 32768);
    bf16* Q   = P + 20971520;
    bf16* Wbig   = Q + 10485760;
    bf16* dec2pk = P + 10485760;
    bf16* pk_e0 = Wbig;                 //   2048
    bf16* pk_e1 = Wbig + 2048;          //  73728
    bf16* pk_e2 = Wbig + 75776;         // 294912
    bf16* pk_d0 = Wbig + 370688;        // 294912
    bf16* pk_d1 = Wbig + 665600;        //  73728

    // ---- prologue: zero z accumulator, pack weights to MFMA fragment layout
    zero_k<<<16, 256, 0, stream>>>(zf, 4096);
    pack_k<<<8,    256, 0, stream>>>(encW0, pk_e0,   27,  64,  4,  1);
    pack_k<<<288,  256, 0, stream>>>(encW1, pk_e1,  576, 128,  8, 18);
    pack_k<<<1152, 256, 0, stream>>>(encW2, pk_e2, 1152, 256, 16, 36);
    pack_k<<<1152, 256, 0, stream>>>(decW0, pk_d0, 2304, 128,  8, 72);
    pack_k<<<288,  256, 0, stream>>>(decW1, pk_d1, 1152,  64,  4, 36);

    // ---- encoder
    mconv0_k<<<5120, 256, 0, stream>>>(x, idx0, pk_e0, encb0, P, 20480, 20480);
    pool_k<<<2560, 256, 0, stream>>>(P, dpi0, dpw0, Q, 5120, 20480, 64);
    mconv_k<bf16, 64, 128, 2, true><<<2560, 256, 0, stream>>>(Q, idx1, pk_e1, encb1, P, 5120, 5120);
    pool_k<<<1280, 256, 0, stream>>>(P, dpi1, dpw1, Q, 1280, 5120, 128);
    mconv_k<bf16, 128, 256, 2, true><<<640, 256, 0, stream>>>(Q, idx2, pk_e2, encb2, P, 1280, 1280);
    pool_k<<<640, 256, 0, stream>>>(P, dpi2, dpw2, Q, 320, 1280, 256);

    // ---- latent
    zacc_k<<<320, 256, 0, stream>>>(Q, Wz, zf);
    zfin_k<<<16, 256, 0, stream>>>(zf, bz, outz);
    dproj_k<<<320, 256, 0, stream>>>(zf, Wp, bp, P);   // d -> P [16,320,256]

    // ---- decoder
    pool_k<<<2560, 256, 0, stream>>>(P, upi0, upw0, Q, 1280, 320, 256);
    mconv_k<bf16, 256, 128, 2, true><<<640, 256, 0, stream>>>(Q, idx2, pk_d0, decb0, P, 1280, 1280);
    pool_k<<<5120, 256, 0, stream>>>(P, upi1, upw1, Q, 5120, 1280, 128);
    mconv_k<bf16, 128, 64, 2, true><<<2560, 256, 0, stream>>>(Q, idx1, pk_d1, decb1, P, 5120, 5120);
    pack_k<<<36, 256, 0, stream>>>(decW2, dec2pk, 576, 3, 1, 18);
    pool_k<<<10240, 256, 0, stream>>>(P, upi2, upw2, Q, 20480, 5120, 64);
    mconv_k<float, 64, 3, 1, false><<<5120, 256, 0, stream>>>(Q, idx0, dec2pk, decb2, outy, 20480, 20480);
}